// Round 14
// baseline (1432.230 us; speedup 1.0000x reference)
//
#include <hip/hip_runtime.h>
#include <hip/hip_bf16.h>

typedef short  short8  __attribute__((ext_vector_type(8)));
typedef float  float4v __attribute__((ext_vector_type(4)));
typedef uint   uint4v  __attribute__((ext_vector_type(4)));

#define N_ROWS 4096
#define DDIM   64
#define NKB    (N_ROWS / 64)
#define NSPLIT 16              // wave = key-split; 16 waves/block
#define NT4    (NKB / NSPLIT)  // 4 key-blocks per wave per step
#define HSTEP  0.125f
#define SIG0   0.001f
#define LOG2E  1.44269504088896340736f

__device__ __forceinline__ ushort f2bf(float f) {
    __hip_bfloat16 h = __float2bfloat16(f);
    return *reinterpret_cast<ushort*>(&h);
}
__device__ __forceinline__ float bf2f(ushort u) {
    return __uint_as_float(((unsigned)u) << 16);
}
__device__ __forceinline__ float4v mfma16(short8 a, short8 b, float4v c) {
    return __builtin_amdgcn_mfma_f32_16x16x32_bf16(a, b, c, 0, 0, 0);
}

// ---------------------------------------------------------------------------
// Prep (fused stats + pack): x0sq, x0sum, MFMA-fragment packing (hi/lo bf16).
// Apk[kb][ks][half][lane]: lane(g,qi) holds x0[kb*64+ks*16+qi][half*32+g*8+j].
// Bpk[kb][ks2][dsub][lane]: lane(g,qi) holds x0[kb*64+ks2*32+g*8+j][dsub*16+qi].
// ---------------------------------------------------------------------------
__global__ __launch_bounds__(256) void prep_pack_kernel(
    const float* __restrict__ x0,
    short8* __restrict__ Apk_h, short8* __restrict__ Apk_l,
    short8* __restrict__ Bpk_h, short8* __restrict__ Bpk_l,
    float* __restrict__ x0sq, float* __restrict__ x0sum)
{
    __shared__ float xt_[64][65];
    __shared__ float cs[64];
    const int tid  = threadIdx.x;
    const int kb64 = blockIdx.x;
    if (tid < 64) cs[tid] = 0.f;
    __syncthreads();
    {
        const int r = tid >> 2, c0 = (tid & 3) * 16;
        const float4* src = (const float4*)(x0 + ((size_t)(kb64 * 64 + r)) * DDIM + c0);
        float ss = 0.f;
#pragma unroll
        for (int k = 0; k < 4; ++k) {
            float4 v = src[k];
            xt_[r][c0 + 4 * k + 0] = v.x; xt_[r][c0 + 4 * k + 1] = v.y;
            xt_[r][c0 + 4 * k + 2] = v.z; xt_[r][c0 + 4 * k + 3] = v.w;
            ss += v.x * v.x + v.y * v.y + v.z * v.z + v.w * v.w;
            atomicAdd(&cs[c0 + 4 * k + 0], v.x);
            atomicAdd(&cs[c0 + 4 * k + 1], v.y);
            atomicAdd(&cs[c0 + 4 * k + 2], v.z);
            atomicAdd(&cs[c0 + 4 * k + 3], v.w);
        }
        ss += __shfl_xor(ss, 1, 64);
        ss += __shfl_xor(ss, 2, 64);
        if ((tid & 3) == 0) x0sq[kb64 * 64 + r] = ss;
    }
    __syncthreads();
    if (tid < 64) atomicAdd(&x0sum[tid], cs[tid]);

    const int w = tid >> 6, lane = tid & 63, qi = lane & 15, g = lane >> 4;
#pragma unroll
    for (int half = 0; half < 2; ++half) {
        short8 h, l;
#pragma unroll
        for (int j = 0; j < 8; ++j) {
            float v = xt_[w * 16 + qi][half * 32 + g * 8 + j];
            ushort hh = f2bf(v);
            h[j] = (short)hh;
            l[j] = (short)f2bf(v - bf2f(hh));
        }
        size_t idx = (((size_t)kb64 * 4 + w) * 2 + half) * 64 + lane;
        Apk_h[idx] = h; Apk_l[idx] = l;
    }
#pragma unroll
    for (int pp = 0; pp < 2; ++pp) {
        int pw = w + pp * 4;
        int ks2 = pw >> 2, dsub = pw & 3;
        short8 h, l;
#pragma unroll
        for (int j = 0; j < 8; ++j) {
            float v = xt_[ks2 * 32 + g * 8 + j][dsub * 16 + qi];
            ushort hh = f2bf(v);
            h[j] = (short)hh;
            l[j] = (short)f2bf(v - bf2f(hh));
        }
        size_t idx = (((size_t)kb64 * 2 + ks2) * 4 + dsub) * 64 + lane;
        Bpk_h[idx] = h; Bpk_l[idx] = l;
    }
}

// ---------------------------------------------------------------------------
// Persistent flow kernel (R13 structure + R14 two-phase softmax, exp2 domain).
// 256 blocks x 1024 thr; block owns 16 rows for all 7 Heun steps.
// Per step per wave: (1) QK for ALL 4 key-blocks -> sc[16][4] (deep load
// pipelining, no per-tile dependency); (2) ONE max/exp2/sum pass (no online
// rescale -- pvacc accumulates unscaled); (3) pack+relayout+PV per tile.
// Scores are in base-2 (log2e folded into scale/beta): softmax ratios are
// mathematically identical; saves the mul inside every __expf.
// ---------------------------------------------------------------------------
__global__ __launch_bounds__(1024) void flow_kernel(
    const float* __restrict__ z, const float* __restrict__ x0sum,
    const short8* __restrict__ Apk_h, const short8* __restrict__ Apk_l,
    const short8* __restrict__ Bpk_h, const short8* __restrict__ Bpk_l,
    const float* __restrict__ x0sq, float* __restrict__ xt_out)
{
    __shared__ float xt_lds[16][65];
    __shared__ float G1_lds[16][65];
    __shared__ float part[NSPLIT][16][66];
    __shared__ float m_lds[NSPLIT][17];
    __shared__ float l_lds[NSPLIT][17];

    const int tid  = threadIdx.x;
    const int w    = tid >> 6;      // wave = key-split, 0..15
    const int lane = tid & 63;
    const int g    = lane >> 4;
    const int qi   = lane & 15;
    const int crow = tid >> 6;      // combine row
    const int d    = tid & 63;      // combine dim
    const int rowbase = blockIdx.x * 16;

    // ---- init: xt = z; G1 = G(t=1) closed form (scores==0 -> qt=mean(x0)) ----
    {
        float zv = z[(size_t)(rowbase + crow) * DDIM + d];
        xt_lds[crow][d] = zv;
        G1_lds[crow][d] = (1.0f - SIG0) * zv - x0sum[d] * (1.0f / 4096.0f);
    }
    __syncthreads();

    for (int step = 0; step < 7; ++step) {
        const float t  = (float)(7 - step) * 0.125f;
        const float al = 1.0f - t;
        const float sg = SIG0 + (1.0f - SIG0) * t;
        const float scale2 = (al / (sg * sg)) * LOG2E;            // base-2 scores
        const float beta2  = (al * al / (2.0f * sg * sg)) * LOG2E;
        const float inv_sig = 1.0f / sg;

        // ---- x B-frags from LDS: x = xt - H*G1, d = ds*32 + g*8 + j ----
        short8 xbh[2], xbl[2];
#pragma unroll
        for (int ds_ = 0; ds_ < 2; ++ds_) {
            const int d0 = ds_ * 32 + g * 8;
#pragma unroll
            for (int j = 0; j < 8; ++j) {
                float x = xt_lds[qi][d0 + j] - HSTEP * G1_lds[qi][d0 + j];
                ushort h = f2bf(x);
                xbh[ds_][j] = (short)h;
                xbl[ds_][j] = (short)f2bf(x - bf2f(h));
            }
        }

        // ---- phase 1: QK^T for all 4 key-blocks -> sc[16][4] (base-2) ----
        // key = (w*NT4 + (ks>>2))*64 + (ks&3)*16 + g*4 + r
        float sc[16][4];
#pragma unroll
        for (int ks = 0; ks < 16; ++ks) {
            const int kbi = w * NT4 + (ks >> 2);
            const int ksl = ks & 3;
            const size_t ai = (((size_t)kbi * 4 + ksl) * 2) * 64 + lane;
            short8 Ah0 = Apk_h[ai];
            short8 Ah1 = Apk_h[ai + 64];
            short8 Al0 = Apk_l[ai];
            short8 Al1 = Apk_l[ai + 64];
            float4v acc = (float4v){0.f, 0.f, 0.f, 0.f};
            __builtin_amdgcn_s_setprio(1);
            acc = mfma16(Ah0, xbh[0], acc);
            acc = mfma16(Ah1, xbh[1], acc);
            acc = mfma16(Al0, xbh[0], acc);
            acc = mfma16(Al1, xbh[1], acc);
            acc = mfma16(Ah0, xbl[0], acc);
            acc = mfma16(Ah1, xbl[1], acc);
            __builtin_amdgcn_s_setprio(0);
            const float4 sq = *(const float4*)(x0sq + kbi * 64 + ksl * 16 + g * 4);
            sc[ks][0] = scale2 * acc[0] - beta2 * sq.x;
            sc[ks][1] = scale2 * acc[1] - beta2 * sq.y;
            sc[ks][2] = scale2 * acc[2] - beta2 * sq.z;
            sc[ks][3] = scale2 * acc[3] - beta2 * sq.w;
        }

        // ---- phase 2: single softmax pass over all 256 keys (no rescale) ----
        float m = sc[0][0];
#pragma unroll
        for (int ks = 0; ks < 16; ++ks)
#pragma unroll
            for (int r = 0; r < 4; ++r) m = fmaxf(m, sc[ks][r]);
        m = fmaxf(m, __shfl_xor(m, 16, 64));
        m = fmaxf(m, __shfl_xor(m, 32, 64));
        float lsum = 0.f;
#pragma unroll
        for (int ks = 0; ks < 16; ++ks)
#pragma unroll
            for (int r = 0; r < 4; ++r) {
                sc[ks][r] = exp2f(sc[ks][r] - m);   // sc now holds p
                lsum += sc[ks][r];
            }
        lsum += __shfl_xor(lsum, 16, 64);
        lsum += __shfl_xor(lsum, 32, 64);

        // ---- phase 3: pack + relayout + PV per key-block (pure accumulate) ----
        float4v pvacc[4];
#pragma unroll
        for (int dd = 0; dd < 4; ++dd) pvacc[dd] = (float4v){0.f, 0.f, 0.f, 0.f};
#pragma unroll
        for (int tile = 0; tile < NT4; ++tile) {
            const int kbi = w * NT4 + tile;
            uint pkh[4][2], pkl[4][2];
#pragma unroll
            for (int ks = 0; ks < 4; ++ks)
#pragma unroll
                for (int pr = 0; pr < 2; ++pr) {
                    float f0 = sc[tile * 4 + ks][2 * pr];
                    float f1 = sc[tile * 4 + ks][2 * pr + 1];
                    ushort h0 = f2bf(f0), h1 = f2bf(f1);
                    pkh[ks][pr] = (uint)h0 | ((uint)h1 << 16);
                    ushort e0 = f2bf(f0 - bf2f(h0)), e1 = f2bf(f1 - bf2f(h1));
                    pkl[ks][pr] = (uint)e0 | ((uint)e1 << 16);
                }
#pragma unroll
            for (int ks2 = 0; ks2 < 2; ++ks2) {
                uint4v pah, pal;
#pragma unroll
                for (int c = 0; c < 4; ++c) {
                    const int src = (2 * (g & 1) + (c >> 1)) * 16 + qi;
                    uint h0 = (uint)__shfl((int)pkh[2 * ks2][c & 1], src, 64);
                    uint h1 = (uint)__shfl((int)pkh[2 * ks2 + 1][c & 1], src, 64);
                    pah[c] = (g >= 2) ? h1 : h0;
                    uint l0 = (uint)__shfl((int)pkl[2 * ks2][c & 1], src, 64);
                    uint l1 = (uint)__shfl((int)pkl[2 * ks2 + 1][c & 1], src, 64);
                    pal[c] = (g >= 2) ? l1 : l0;
                }
                const short8 PAh = __builtin_bit_cast(short8, pah);
                const short8 PAl = __builtin_bit_cast(short8, pal);
#pragma unroll
                for (int dsub = 0; dsub < 4; ++dsub) {
                    const size_t bi = (((size_t)kbi * 2 + ks2) * 4 + dsub) * 64 + lane;
                    short8 Bh = Bpk_h[bi];
                    short8 Bl = Bpk_l[bi];
                    __builtin_amdgcn_s_setprio(1);
                    pvacc[dsub] = mfma16(PAh, Bh, pvacc[dsub]);
                    pvacc[dsub] = mfma16(PAh, Bl, pvacc[dsub]);
                    pvacc[dsub] = mfma16(PAl, Bh, pvacc[dsub]);
                    __builtin_amdgcn_s_setprio(0);
                }
            }
        }

        // ---- partials -> LDS: PV D row = g*4 + r, col d = dsub*16 + qi ----
#pragma unroll
        for (int dsub = 0; dsub < 4; ++dsub)
#pragma unroll
            for (int r = 0; r < 4; ++r)
                part[w][g * 4 + r][dsub * 16 + qi] = pvacc[dsub][r];
        if (g == 0) { m_lds[w][qi] = m; l_lds[w][qi] = lsum; }
        __syncthreads();

        // ---- in-block combine (base-2) + Heun update (thread = (crow, d)) ----
        {
            float mstar = m_lds[0][crow];
#pragma unroll
            for (int i = 1; i < NSPLIT; ++i) mstar = fmaxf(mstar, m_lds[i][crow]);
            float L = 0.f, num = 0.f;
#pragma unroll
            for (int i = 0; i < NSPLIT; ++i) {
                float e = exp2f(m_lds[i][crow] - mstar);
                L   += l_lds[i][crow] * e;
                num += part[i][crow][d] * e;
            }
            const float qt  = num / L;
            const float g1v = G1_lds[crow][d];
            const float xv  = xt_lds[crow][d] - HSTEP * g1v;
            const float g2  = ((1.0f - SIG0) * xv - qt) * inv_sig;
            xt_lds[crow][d] -= (g1v + g2) * (HSTEP * 0.5f);
            G1_lds[crow][d]  = g2;
        }
        __syncthreads();
    }

    // ---- final write ----
    xt_out[(size_t)(rowbase + crow) * DDIM + d] = xt_lds[crow][d];
}

// ---------------------------------------------------------------------------
extern "C" void kernel_launch(void* const* d_in, const int* in_sizes, int n_in,
                              void* d_out, int out_size, void* d_ws, size_t ws_size,
                              hipStream_t stream) {
    const float* z  = (const float*)d_in[0];
    const float* x0 = (const float*)d_in[1];
    float* xt = (float*)d_out;

    // ---- workspace layout (256B aligned); ~8.4MB ----
    char* p = (char*)d_ws;
    auto alloc = [&](size_t bytes) {
        char* q = p; p += (bytes + 255) & ~(size_t)255; return q;
    };
    float*  x0sq  = (float*)alloc((size_t)N_ROWS * 4);
    float*  x0sum = (float*)alloc(64 * 4);
    short8* Apk_h = (short8*)alloc((size_t)NKB * 4 * 2 * 64 * 16);
    short8* Apk_l = (short8*)alloc((size_t)NKB * 4 * 2 * 64 * 16);
    short8* Bpk_h = (short8*)alloc((size_t)NKB * 2 * 4 * 64 * 16);
    short8* Bpk_l = (short8*)alloc((size_t)NKB * 2 * 4 * 64 * 16);

    hipMemsetAsync(x0sum, 0, 64 * 4, stream);
    prep_pack_kernel<<<NKB, 256, 0, stream>>>(x0, Apk_h, Apk_l, Bpk_h, Bpk_l,
                                              x0sq, x0sum);
    flow_kernel<<<N_ROWS / 16, 1024, 0, stream>>>(z, x0sum, Apk_h, Apk_l,
                                                  Bpk_h, Bpk_l, x0sq, xt);
}

// Round 15
// 1430.331 us; speedup vs baseline: 1.0013x; 1.0013x over previous
//
#include <hip/hip_runtime.h>
#include <hip/hip_bf16.h>

typedef short  short8  __attribute__((ext_vector_type(8)));
typedef float  float4v __attribute__((ext_vector_type(4)));
typedef uint   uint4v  __attribute__((ext_vector_type(4)));

#define N_ROWS 4096
#define DDIM   64
#define NKB    (N_ROWS / 64)
#define NSPLIT 16              // wave = key-split; 16 waves/block
#define NT4    (NKB / NSPLIT)  // 4 key-blocks per wave per step
#define HSTEP  0.125f
#define SIG0   0.001f
#define LOG2E  1.44269504088896340736f

__device__ __forceinline__ ushort f2bf(float f) {
    __hip_bfloat16 h = __float2bfloat16(f);
    return *reinterpret_cast<ushort*>(&h);
}
__device__ __forceinline__ float bf2f(ushort u) {
    return __uint_as_float(((unsigned)u) << 16);
}
__device__ __forceinline__ float4v mfma16(short8 a, short8 b, float4v c) {
    return __builtin_amdgcn_mfma_f32_16x16x32_bf16(a, b, c, 0, 0, 0);
}

// ---------------------------------------------------------------------------
// Prep (fused stats + pack): x0sq, x0sum, MFMA-fragment packing (hi/lo bf16).
// Apk[kb][ks][half][lane]: lane(g,qi) holds x0[kb*64+ks*16+qi][half*32+g*8+j].
// Bpk[kb][ks2][dsub][lane]: lane(g,qi) holds x0[kb*64+ks2*32+g*8+j][dsub*16+qi].
// ---------------------------------------------------------------------------
__global__ __launch_bounds__(256) void prep_pack_kernel(
    const float* __restrict__ x0,
    short8* __restrict__ Apk_h, short8* __restrict__ Apk_l,
    short8* __restrict__ Bpk_h, short8* __restrict__ Bpk_l,
    float* __restrict__ x0sq, float* __restrict__ x0sum)
{
    __shared__ float xt_[64][65];
    __shared__ float cs[64];
    const int tid  = threadIdx.x;
    const int kb64 = blockIdx.x;
    if (tid < 64) cs[tid] = 0.f;
    __syncthreads();
    {
        const int r = tid >> 2, c0 = (tid & 3) * 16;
        const float4* src = (const float4*)(x0 + ((size_t)(kb64 * 64 + r)) * DDIM + c0);
        float ss = 0.f;
#pragma unroll
        for (int k = 0; k < 4; ++k) {
            float4 v = src[k];
            xt_[r][c0 + 4 * k + 0] = v.x; xt_[r][c0 + 4 * k + 1] = v.y;
            xt_[r][c0 + 4 * k + 2] = v.z; xt_[r][c0 + 4 * k + 3] = v.w;
            ss += v.x * v.x + v.y * v.y + v.z * v.z + v.w * v.w;
            atomicAdd(&cs[c0 + 4 * k + 0], v.x);
            atomicAdd(&cs[c0 + 4 * k + 1], v.y);
            atomicAdd(&cs[c0 + 4 * k + 2], v.z);
            atomicAdd(&cs[c0 + 4 * k + 3], v.w);
        }
        ss += __shfl_xor(ss, 1, 64);
        ss += __shfl_xor(ss, 2, 64);
        if ((tid & 3) == 0) x0sq[kb64 * 64 + r] = ss;
    }
    __syncthreads();
    if (tid < 64) atomicAdd(&x0sum[tid], cs[tid]);

    const int w = tid >> 6, lane = tid & 63, qi = lane & 15, g = lane >> 4;
#pragma unroll
    for (int half = 0; half < 2; ++half) {
        short8 h, l;
#pragma unroll
        for (int j = 0; j < 8; ++j) {
            float v = xt_[w * 16 + qi][half * 32 + g * 8 + j];
            ushort hh = f2bf(v);
            h[j] = (short)hh;
            l[j] = (short)f2bf(v - bf2f(hh));
        }
        size_t idx = (((size_t)kb64 * 4 + w) * 2 + half) * 64 + lane;
        Apk_h[idx] = h; Apk_l[idx] = l;
    }
#pragma unroll
    for (int pp = 0; pp < 2; ++pp) {
        int pw = w + pp * 4;
        int ks2 = pw >> 2, dsub = pw & 3;
        short8 h, l;
#pragma unroll
        for (int j = 0; j < 8; ++j) {
            float v = xt_[ks2 * 32 + g * 8 + j][dsub * 16 + qi];
            ushort hh = f2bf(v);
            h[j] = (short)hh;
            l[j] = (short)f2bf(v - bf2f(hh));
        }
        size_t idx = (((size_t)kb64 * 2 + ks2) * 4 + dsub) * 64 + lane;
        Bpk_h[idx] = h; Bpk_l[idx] = l;
    }
}

// ---------------------------------------------------------------------------
// Persistent flow kernel (R14 two-phase + exp2, R15 fix: launch_bounds(1024,4)
// -> 4 waves/EU = 1 block/CU = 16 waves/CU (same as R13) but VGPR budget 128.
// R14 lesson: default launch_bounds targeted 8 waves/EU -> 64-VGPR cap ->
// sc[16][4] spilled to scratch (2.25GB fetch/dispatch, 6.7x slowdown).
// Per step per wave: (1) QK for ALL 4 key-blocks -> sc[16][4]; (2) ONE
// max/exp2/sum pass (no online rescale); (3) pack+relayout+PV per tile.
// ---------------------------------------------------------------------------
__global__ __launch_bounds__(1024, 4) void flow_kernel(
    const float* __restrict__ z, const float* __restrict__ x0sum,
    const short8* __restrict__ Apk_h, const short8* __restrict__ Apk_l,
    const short8* __restrict__ Bpk_h, const short8* __restrict__ Bpk_l,
    const float* __restrict__ x0sq, float* __restrict__ xt_out)
{
    __shared__ float xt_lds[16][65];
    __shared__ float G1_lds[16][65];
    __shared__ float part[NSPLIT][16][66];
    __shared__ float m_lds[NSPLIT][17];
    __shared__ float l_lds[NSPLIT][17];

    const int tid  = threadIdx.x;
    const int w    = tid >> 6;      // wave = key-split, 0..15
    const int lane = tid & 63;
    const int g    = lane >> 4;
    const int qi   = lane & 15;
    const int crow = tid >> 6;      // combine row
    const int d    = tid & 63;      // combine dim
    const int rowbase = blockIdx.x * 16;

    // ---- init: xt = z; G1 = G(t=1) closed form (scores==0 -> qt=mean(x0)) ----
    {
        float zv = z[(size_t)(rowbase + crow) * DDIM + d];
        xt_lds[crow][d] = zv;
        G1_lds[crow][d] = (1.0f - SIG0) * zv - x0sum[d] * (1.0f / 4096.0f);
    }
    __syncthreads();

    for (int step = 0; step < 7; ++step) {
        const float t  = (float)(7 - step) * 0.125f;
        const float al = 1.0f - t;
        const float sg = SIG0 + (1.0f - SIG0) * t;
        const float scale2 = (al / (sg * sg)) * LOG2E;            // base-2 scores
        const float beta2  = (al * al / (2.0f * sg * sg)) * LOG2E;
        const float inv_sig = 1.0f / sg;

        // ---- x B-frags from LDS: x = xt - H*G1, d = ds*32 + g*8 + j ----
        short8 xbh[2], xbl[2];
#pragma unroll
        for (int ds_ = 0; ds_ < 2; ++ds_) {
            const int d0 = ds_ * 32 + g * 8;
#pragma unroll
            for (int j = 0; j < 8; ++j) {
                float x = xt_lds[qi][d0 + j] - HSTEP * G1_lds[qi][d0 + j];
                ushort h = f2bf(x);
                xbh[ds_][j] = (short)h;
                xbl[ds_][j] = (short)f2bf(x - bf2f(h));
            }
        }

        // ---- phase 1: QK^T for all 4 key-blocks -> sc[16][4] (base-2) ----
        float sc[16][4];
#pragma unroll
        for (int ks = 0; ks < 16; ++ks) {
            const int kbi = w * NT4 + (ks >> 2);
            const int ksl = ks & 3;
            const size_t ai = (((size_t)kbi * 4 + ksl) * 2) * 64 + lane;
            short8 Ah0 = Apk_h[ai];
            short8 Ah1 = Apk_h[ai + 64];
            short8 Al0 = Apk_l[ai];
            short8 Al1 = Apk_l[ai + 64];
            float4v acc = (float4v){0.f, 0.f, 0.f, 0.f};
            __builtin_amdgcn_s_setprio(1);
            acc = mfma16(Ah0, xbh[0], acc);
            acc = mfma16(Ah1, xbh[1], acc);
            acc = mfma16(Al0, xbh[0], acc);
            acc = mfma16(Al1, xbh[1], acc);
            acc = mfma16(Ah0, xbl[0], acc);
            acc = mfma16(Ah1, xbl[1], acc);
            __builtin_amdgcn_s_setprio(0);
            const float4 sq = *(const float4*)(x0sq + kbi * 64 + ksl * 16 + g * 4);
            sc[ks][0] = scale2 * acc[0] - beta2 * sq.x;
            sc[ks][1] = scale2 * acc[1] - beta2 * sq.y;
            sc[ks][2] = scale2 * acc[2] - beta2 * sq.z;
            sc[ks][3] = scale2 * acc[3] - beta2 * sq.w;
        }

        // ---- phase 2: single softmax pass over all 256 keys (no rescale) ----
        float m = sc[0][0];
#pragma unroll
        for (int ks = 0; ks < 16; ++ks)
#pragma unroll
            for (int r = 0; r < 4; ++r) m = fmaxf(m, sc[ks][r]);
        m = fmaxf(m, __shfl_xor(m, 16, 64));
        m = fmaxf(m, __shfl_xor(m, 32, 64));
        float lsum = 0.f;
#pragma unroll
        for (int ks = 0; ks < 16; ++ks)
#pragma unroll
            for (int r = 0; r < 4; ++r) {
                sc[ks][r] = exp2f(sc[ks][r] - m);   // sc now holds p
                lsum += sc[ks][r];
            }
        lsum += __shfl_xor(lsum, 16, 64);
        lsum += __shfl_xor(lsum, 32, 64);

        // ---- phase 3: pack + relayout + PV per key-block (pure accumulate) ----
        float4v pvacc[4];
#pragma unroll
        for (int dd = 0; dd < 4; ++dd) pvacc[dd] = (float4v){0.f, 0.f, 0.f, 0.f};
#pragma unroll
        for (int tile = 0; tile < NT4; ++tile) {
            const int kbi = w * NT4 + tile;
            uint pkh[4][2], pkl[4][2];
#pragma unroll
            for (int ks = 0; ks < 4; ++ks)
#pragma unroll
                for (int pr = 0; pr < 2; ++pr) {
                    float f0 = sc[tile * 4 + ks][2 * pr];
                    float f1 = sc[tile * 4 + ks][2 * pr + 1];
                    ushort h0 = f2bf(f0), h1 = f2bf(f1);
                    pkh[ks][pr] = (uint)h0 | ((uint)h1 << 16);
                    ushort e0 = f2bf(f0 - bf2f(h0)), e1 = f2bf(f1 - bf2f(h1));
                    pkl[ks][pr] = (uint)e0 | ((uint)e1 << 16);
                }
#pragma unroll
            for (int ks2 = 0; ks2 < 2; ++ks2) {
                uint4v pah, pal;
#pragma unroll
                for (int c = 0; c < 4; ++c) {
                    const int src = (2 * (g & 1) + (c >> 1)) * 16 + qi;
                    uint h0 = (uint)__shfl((int)pkh[2 * ks2][c & 1], src, 64);
                    uint h1 = (uint)__shfl((int)pkh[2 * ks2 + 1][c & 1], src, 64);
                    pah[c] = (g >= 2) ? h1 : h0;
                    uint l0 = (uint)__shfl((int)pkl[2 * ks2][c & 1], src, 64);
                    uint l1 = (uint)__shfl((int)pkl[2 * ks2 + 1][c & 1], src, 64);
                    pal[c] = (g >= 2) ? l1 : l0;
                }
                const short8 PAh = __builtin_bit_cast(short8, pah);
                const short8 PAl = __builtin_bit_cast(short8, pal);
#pragma unroll
                for (int dsub = 0; dsub < 4; ++dsub) {
                    const size_t bi = (((size_t)kbi * 2 + ks2) * 4 + dsub) * 64 + lane;
                    short8 Bh = Bpk_h[bi];
                    short8 Bl = Bpk_l[bi];
                    __builtin_amdgcn_s_setprio(1);
                    pvacc[dsub] = mfma16(PAh, Bh, pvacc[dsub]);
                    pvacc[dsub] = mfma16(PAh, Bl, pvacc[dsub]);
                    pvacc[dsub] = mfma16(PAl, Bh, pvacc[dsub]);
                    __builtin_amdgcn_s_setprio(0);
                }
            }
        }

        // ---- partials -> LDS: PV D row = g*4 + r, col d = dsub*16 + qi ----
#pragma unroll
        for (int dsub = 0; dsub < 4; ++dsub)
#pragma unroll
            for (int r = 0; r < 4; ++r)
                part[w][g * 4 + r][dsub * 16 + qi] = pvacc[dsub][r];
        if (g == 0) { m_lds[w][qi] = m; l_lds[w][qi] = lsum; }
        __syncthreads();

        // ---- in-block combine (base-2) + Heun update (thread = (crow, d)) ----
        {
            float mstar = m_lds[0][crow];
#pragma unroll
            for (int i = 1; i < NSPLIT; ++i) mstar = fmaxf(mstar, m_lds[i][crow]);
            float L = 0.f, num = 0.f;
#pragma unroll
            for (int i = 0; i < NSPLIT; ++i) {
                float e = exp2f(m_lds[i][crow] - mstar);
                L   += l_lds[i][crow] * e;
                num += part[i][crow][d] * e;
            }
            const float qt  = num / L;
            const float g1v = G1_lds[crow][d];
            const float xv  = xt_lds[crow][d] - HSTEP * g1v;
            const float g2  = ((1.0f - SIG0) * xv - qt) * inv_sig;
            xt_lds[crow][d] -= (g1v + g2) * (HSTEP * 0.5f);
            G1_lds[crow][d]  = g2;
        }
        __syncthreads();
    }

    // ---- final write ----
    xt_out[(size_t)(rowbase + crow) * DDIM + d] = xt_lds[crow][d];
}

// ---------------------------------------------------------------------------
extern "C" void kernel_launch(void* const* d_in, const int* in_sizes, int n_in,
                              void* d_out, int out_size, void* d_ws, size_t ws_size,
                              hipStream_t stream) {
    const float* z  = (const float*)d_in[0];
    const float* x0 = (const float*)d_in[1];
    float* xt = (float*)d_out;

    // ---- workspace layout (256B aligned); ~8.4MB ----
    char* p = (char*)d_ws;
    auto alloc = [&](size_t bytes) {
        char* q = p; p += (bytes + 255) & ~(size_t)255; return q;
    };
    float*  x0sq  = (float*)alloc((size_t)N_ROWS * 4);
    float*  x0sum = (float*)alloc(64 * 4);
    short8* Apk_h = (short8*)alloc((size_t)NKB * 4 * 2 * 64 * 16);
    short8* Apk_l = (short8*)alloc((size_t)NKB * 4 * 2 * 64 * 16);
    short8* Bpk_h = (short8*)alloc((size_t)NKB * 2 * 4 * 64 * 16);
    short8* Bpk_l = (short8*)alloc((size_t)NKB * 2 * 4 * 64 * 16);

    hipMemsetAsync(x0sum, 0, 64 * 4, stream);
    prep_pack_kernel<<<NKB, 256, 0, stream>>>(x0, Apk_h, Apk_l, Bpk_h, Bpk_l,
                                              x0sq, x0sum);
    flow_kernel<<<N_ROWS / 16, 1024, 0, stream>>>(z, x0sum, Apk_h, Apk_l,
                                                  Bpk_h, Bpk_l, x0sq, xt);
}